// Round 7
// baseline (241.297 us; speedup 1.0000x reference)
//
#include <hip/hip_runtime.h>

#define NUM_INST 64
#define BLOCK 256
#define NWAVES 4
#define GRID 2048

typedef float f32x4 __attribute__((ext_vector_type(4)));
typedef short s16x8 __attribute__((ext_vector_type(8)));
typedef int   i32x4 __attribute__((ext_vector_type(4)));

union FragU { i32x4 i; s16x8 s; };

// pack {bf16_rne(v), bf16_rne(v - bf16(v))} into one u32: hi in low16 (even k-slot),
// lo in high16 (odd k-slot). RNE keeps the split error unbiased (no linear drift).
__device__ __forceinline__ unsigned hilo_pack(float v) {
    unsigned h, p;
    asm("v_cvt_pk_bf16_f32 %0, %1, %1" : "=v"(h) : "v"(v));
    const float r = v - __uint_as_float(h << 16);
    asm("v_cvt_pk_bf16_f32 %0, %1, %2" : "=v"(p) : "v"(v), "v"(r));
    return p;
}

__global__ __launch_bounds__(BLOCK) void vsl_main(const float* __restrict__ rows,
                                                  const int* __restrict__ labels,
                                                  float* __restrict__ gacc, int n) {
    const int tid = threadIdx.x;
    const int w = tid >> 6;
    const int lane = tid & 63;
    const int g = lane >> 4;   // k-group 0..3
    const int c = lane & 15;   // B col (stat) / A row (label within 16-tile)
    const int cc = c & 7;

    // C1 = Onehot x [v(8) | ones | 0...]  -> sums + count
    // C2 = Onehot x [v^2(8) | 0...]      -> per-dim sum of squares (ssq after col-sum)
    f32x4 accS[4], accQ[4];
#pragma unroll
    for (int t = 0; t < 4; ++t) { accS[t] = (f32x4){0,0,0,0}; accQ[t] = (f32x4){0,0,0,0}; }

    const int waveId = blockIdx.x * NWAVES + w;
    const int nWavesTot = GRID * NWAVES;
    const int nChunks = (n + 15) >> 4;   // 16 rows per MFMA chunk (K=32 k-slots = 16 rows x hi/lo)

    for (int ch = waveId; ch < nChunks; ch += nWavesTot) {
        const int base = ch << 4;
        const int r0 = base + 2 * g;     // this lane covers rows r0, r0+1, r0+8, r0+9
        unsigned b1[4], b2[4];
        int lbl[4];

        if (base + 16 <= n) {
            // fast path: chunk fully valid
            const int2 lp = *(const int2*)(labels + r0);
            const int2 lq = *(const int2*)(labels + r0 + 8);
            lbl[0] = lp.x; lbl[1] = lp.y; lbl[2] = lq.x; lbl[3] = lq.y;
            const float v0 = rows[(r0    ) * 8 + cc];
            const float v1 = rows[(r0 + 1) * 8 + cc];
            const float v2 = rows[(r0 + 8) * 8 + cc];
            const float v3 = rows[(r0 + 9) * 8 + cc];
            if (c < 8) {
                b1[0] = hilo_pack(v0);      b1[1] = hilo_pack(v1);
                b1[2] = hilo_pack(v2);      b1[3] = hilo_pack(v3);
                b2[0] = hilo_pack(v0 * v0); b2[1] = hilo_pack(v1 * v1);
                b2[2] = hilo_pack(v2 * v2); b2[3] = hilo_pack(v3 * v3);
            } else {
                const unsigned one = (c == 8) ? 0x3F80u : 0u;  // count column: 1.0 in hi slot only
                b1[0] = b1[1] = b1[2] = b1[3] = one;
                b2[0] = b2[1] = b2[2] = b2[3] = 0u;
            }
        } else {
            // tail: clamp + zero invalid rows (count column included)
#pragma unroll
            for (int q = 0; q < 4; ++q) {
                const int rq = r0 + (q & 1) + ((q >> 1) * 8);
                const bool ok = rq < n;
                const int sq = ok ? rq : 0;
                const float vq = rows[sq * 8 + cc];
                lbl[q] = ok ? labels[sq] : -1;   // -1 never matches a tile row
                if (c < 8) {
                    b1[q] = ok ? hilo_pack(vq) : 0u;
                    b2[q] = ok ? hilo_pack(vq * vq) : 0u;
                } else {
                    b1[q] = (c == 8 && ok) ? 0x3F80u : 0u;
                    b2[q] = 0u;
                }
            }
        }

        FragU B1, B2;
        B1.i = (i32x4){(int)b1[0], (int)b1[1], (int)b1[2], (int)b1[3]};
        B2.i = (i32x4){(int)b2[0], (int)b2[1], (int)b2[2], (int)b2[3]};

#pragma unroll
        for (int t = 0; t < 4; ++t) {
            const int m = c + 16 * t;   // label this lane's A-row represents
            FragU A;   // one-hot, 1.0 in BOTH k-slots of a row (pairs with hi and lo)
            A.i = (i32x4){ lbl[0] == m ? (int)0x3F803F80 : 0,
                           lbl[1] == m ? (int)0x3F803F80 : 0,
                           lbl[2] == m ? (int)0x3F803F80 : 0,
                           lbl[3] == m ? (int)0x3F803F80 : 0 };
            accS[t] = __builtin_amdgcn_mfma_f32_16x16x32_bf16(A.s, B1.s, accS[t], 0, 0, 0);
            accQ[t] = __builtin_amdgcn_mfma_f32_16x16x32_bf16(A.s, B2.s, accQ[t], 0, 0, 0);
        }
    }

    // ---- epilogue: C/D layout col=lane&15, row=(lane>>4)*4+reg (m89-verified) ----
    __shared__ float red[NWAVES][NUM_INST][12];
#pragma unroll
    for (int t = 0; t < 4; ++t) {
#pragma unroll
        for (int rg = 0; rg < 4; ++rg) {
            const int Lr = 16 * t + 4 * g + rg;
            const float vS = accS[t][rg];
            if (c < 10) red[w][Lr][(c < 8) ? c : (c == 8 ? 9 : 11)] = vS;  // col8=count->slot9
            float sq = accQ[t][rg];   // sum the 8 dim-columns -> ssq
            sq += __shfl_xor(sq, 1, 64);
            sq += __shfl_xor(sq, 2, 64);
            sq += __shfl_xor(sq, 4, 64);
            if (c == 0) red[w][Lr][8] = sq;
        }
    }
    __syncthreads();

    for (int j = tid; j < NUM_INST * 10; j += BLOCK) {
        const int Lb = j / 10;
        const int st = j - Lb * 10;
        float v = 0;
#pragma unroll
        for (int ww = 0; ww < NWAVES; ++ww) v += red[ww][Lb][st];
        atomicAdd(&gacc[j], v);
    }
}

__global__ __launch_bounds__(64) void vsl_final(const float* __restrict__ gacc,
                                                float* __restrict__ out) {
    const int s = threadIdx.x;  // one thread per instance, 1 wave
    float val = 0.0f;
    const float* base = &gacc[s * 10];
    const float cnt = base[9];
    if (s != 0 && cnt > 0.0f) {
        const float ss = base[8];
        float m2 = 0.0f;
#pragma unroll
        for (int d = 0; d < 8; ++d) {
            const float sd = base[d];
            m2 += sd * sd;
        }
        val = (ss - m2 / cnt) / (cnt * 8.0f);
    }
#pragma unroll
    for (int off = 32; off > 0; off >>= 1) val += __shfl_down(val, off, 64);
    if (s == 0) out[0] = val;
}

extern "C" void kernel_launch(void* const* d_in, const int* in_sizes, int n_in,
                              void* d_out, int out_size, void* d_ws, size_t ws_size,
                              hipStream_t stream) {
    const float* variances = (const float*)d_in[0];  // [N, 8] fp32
    const int* labels = (const int*)d_in[1];         // [N] int32
    const int n = in_sizes[1];                       // N
    float* gacc = (float*)d_ws;                      // 640 floats of scratch

    hipMemsetAsync(d_ws, 0, NUM_INST * 10 * sizeof(float), stream);
    vsl_main<<<GRID, BLOCK, 0, stream>>>(variances, labels, gacc, n);
    vsl_final<<<1, 64, 0, stream>>>(gacc, (float*)d_out);
}

// Round 8
// 222.707 us; speedup vs baseline: 1.0835x; 1.0835x over previous
//
#include <hip/hip_runtime.h>

#define NUM_INST 64
#define BLOCK 256
#define NWAVES 4
#define GRID 2048

typedef float f32x4 __attribute__((ext_vector_type(4)));
typedef short s16x8 __attribute__((ext_vector_type(8)));
typedef int   i32x4 __attribute__((ext_vector_type(4)));

union FragU { i32x4 i; s16x8 s; };

// pack {bf16_rne(v), bf16_rne(v - bf16(v))} into one u32 (hi = even k-slot, lo = odd).
// RNE keeps the split error unbiased; fp32 MFMA accumulation makes sums exact to ~2^-24 rel.
__device__ __forceinline__ unsigned hilo_pack(float v) {
    unsigned h, p;
    asm("v_cvt_pk_bf16_f32 %0, %1, %1" : "=v"(h) : "v"(v));
    const float r = v - __uint_as_float(h << 16);
    asm("v_cvt_pk_bf16_f32 %0, %1, %2" : "=v"(p) : "v"(v), "v"(r));
    return p;
}

// one 16-row chunk: B1 = [v | ones | 0], B2 = [v^2 | 0]; A = one-hot(label) per 16-label tile.
// lbl == -1 marks an invalid row: its A entries are 0 in every lane, annihilating junk B.
__device__ __forceinline__ void chunk_mfma(const int* lbl, float v0, float v1,
                                           float v2, float v3, int c,
                                           f32x4* accS, f32x4* accQ) {
    FragU B1, B2;
    if (c < 8) {
        B1.i = (i32x4){(int)hilo_pack(v0), (int)hilo_pack(v1),
                       (int)hilo_pack(v2), (int)hilo_pack(v3)};
        B2.i = (i32x4){(int)hilo_pack(v0 * v0), (int)hilo_pack(v1 * v1),
                       (int)hilo_pack(v2 * v2), (int)hilo_pack(v3 * v3)};
    } else {
        const int one = (c == 8) ? 0x3F80 : 0;  // count column: 1.0 in hi slot only
        B1.i = (i32x4){one, one, one, one};
        B2.i = (i32x4){0, 0, 0, 0};
    }
#pragma unroll
    for (int t = 0; t < 4; ++t) {
        const int m = c + 16 * t;  // label this lane's A-row represents
        FragU A;                   // 1.0 in BOTH 16-bit halves: pairs with hi and lo k-slots
        A.i = (i32x4){ lbl[0] == m ? (int)0x3F803F80 : 0,
                       lbl[1] == m ? (int)0x3F803F80 : 0,
                       lbl[2] == m ? (int)0x3F803F80 : 0,
                       lbl[3] == m ? (int)0x3F803F80 : 0 };
        accS[t] = __builtin_amdgcn_mfma_f32_16x16x32_bf16(A.s, B1.s, accS[t], 0, 0, 0);
        accQ[t] = __builtin_amdgcn_mfma_f32_16x16x32_bf16(A.s, B2.s, accQ[t], 0, 0, 0);
    }
}

__global__ __launch_bounds__(BLOCK) void vsl_main(const float* __restrict__ rows,
                                                  const int* __restrict__ labels,
                                                  float* __restrict__ gacc, int n) {
    // per-wave staging: 512 floats rows + 64 labels = 576 floats; epilogue red aliases sm.
    __shared__ float sm[3072];  // max(4*576 staging, 4*64*12 red) = 12 KB
    const int tid = threadIdx.x;
    const int w = tid >> 6;
    const int lane = tid & 63;
    const int g = lane >> 4;   // k-group 0..3
    const int c = lane & 15;   // B col (stat) / A row (label within 16-tile)
    const int cc = c & 7;

    float* const wrow = sm + w * 576;
    int* const wlab = (int*)(wrow + 512);

    f32x4 accS[4], accQ[4];
#pragma unroll
    for (int t = 0; t < 4; ++t) { accS[t] = (f32x4){0,0,0,0}; accQ[t] = (f32x4){0,0,0,0}; }

    const int waveId = blockIdx.x * NWAVES + w;
    const int step = GRID * NWAVES;
    const int nSC = (n + 63) >> 6;   // super-chunks of 64 rows (4 MFMA chunks)
    const int nFullSC = n >> 6;      // fully in-bounds super-chunks -> staged fast path

    // ---- reg-carried pipeline: issue loads one super-chunk ahead (T14 async-split) ----
    f32x4 pr0 = {0,0,0,0}, pr1 = {0,0,0,0};
    int pl = 0;
    int sc = waveId;
    bool stCur = (sc < nFullSC);
    if (stCur) {
        const float* src = rows + (size_t)sc * 512;
        pr0 = *(const f32x4*)(src + lane * 4);          // 2 KB contiguous per wave:
        pr1 = *(const f32x4*)(src + 256 + lane * 4);    // 2 fully-coalesced dwordx4
        pl = labels[sc * 64 + lane];
    }

    for (; sc < nSC; sc += step) {
        const int scn = sc + step;
        const bool stNext = (scn < nFullSC);

        if (stCur) {
            // write-late: the vmcnt for these regs lands here, one compute-phase after issue
            *(f32x4*)(wrow + lane * 4) = pr0;
            *(f32x4*)(wrow + 256 + lane * 4) = pr1;
            wlab[lane] = pl;
        }
        // issue-early: next super-chunk's HBM latency hides under this one's compute
        f32x4 nr0 = {0,0,0,0}, nr1 = {0,0,0,0};
        int nl = 0;
        if (stNext) {
            const float* src = rows + (size_t)scn * 512;
            nr0 = *(const f32x4*)(src + lane * 4);
            nr1 = *(const f32x4*)(src + 256 + lane * 4);
            nl = labels[scn * 64 + lane];
        }

        if (stCur) {
            // staged path: operands from LDS (2-way bank alias = free; same-addr = broadcast)
#pragma unroll
            for (int ck = 0; ck < 4; ++ck) {
                const float* rc = wrow + ck * 128;
                const int* lc = wlab + ck * 16;
                const int2 lp = *(const int2*)(lc + 2 * g);      // labels r0, r0+1
                const int2 lq = *(const int2*)(lc + 2 * g + 8);  // labels r0+8, r0+9
                const int lbl[4] = {lp.x, lp.y, lq.x, lq.y};
                const float v0 = rc[g * 16 + cc];        // row 2g
                const float v1 = rc[g * 16 + 8 + cc];    // row 2g+1
                const float v2 = rc[g * 16 + 64 + cc];   // row 2g+8
                const float v3 = rc[g * 16 + 72 + cc];   // row 2g+9
                chunk_mfma(lbl, v0, v1, v2, v3, c, accS, accQ);
            }
        } else {
            // partial super-chunk (at most one per wave): clamped direct-global path
            const int base = sc << 6;
#pragma unroll
            for (int ck = 0; ck < 4; ++ck) {
                const int r0 = base + ck * 16 + 2 * g;
                int lbl[4];
                float v[4];
#pragma unroll
                for (int q = 0; q < 4; ++q) {
                    const int rq = r0 + (q & 1) + ((q >> 1) << 3);
                    const bool ok = rq < n;
                    const int rs = ok ? rq : 0;
                    v[q] = rows[(size_t)rs * 8 + cc];
                    lbl[q] = ok ? labels[rs] : -1;  // -1 never matches -> row annihilated
                }
                chunk_mfma(lbl, v[0], v[1], v[2], v[3], c, accS, accQ);
            }
        }
        pr0 = nr0; pr1 = nr1; pl = nl; stCur = stNext;
    }

    // ---- epilogue: C/D layout col=lane&15, row=(lane>>4)*4+reg (m89-verified) ----
    __syncthreads();  // waves finish the loop at different times; red aliases staging memory
    float* const red = sm;  // [NWAVES*64][12]
#pragma unroll
    for (int t = 0; t < 4; ++t) {
#pragma unroll
        for (int rg = 0; rg < 4; ++rg) {
            const int Lr = 16 * t + 4 * g + rg;
            const float vS = accS[t][rg];
            if (c < 10) red[(w * 64 + Lr) * 12 + ((c < 8) ? c : (c == 8 ? 9 : 11))] = vS;
            float sq = accQ[t][rg];  // fold the 8 dim-columns -> ssq
            sq += __shfl_xor(sq, 1, 64);
            sq += __shfl_xor(sq, 2, 64);
            sq += __shfl_xor(sq, 4, 64);
            if (c == 0) red[(w * 64 + Lr) * 12 + 8] = sq;
        }
    }
    __syncthreads();

    for (int j = tid; j < NUM_INST * 10; j += BLOCK) {
        const int Lb = j / 10;
        const int st = j - Lb * 10;
        float v = 0;
#pragma unroll
        for (int ww = 0; ww < NWAVES; ++ww) v += red[(ww * 64 + Lb) * 12 + st];
        atomicAdd(&gacc[j], v);
    }
}

__global__ __launch_bounds__(64) void vsl_final(const float* __restrict__ gacc,
                                                float* __restrict__ out) {
    const int s = threadIdx.x;  // one thread per instance, 1 wave
    float val = 0.0f;
    const float* base = &gacc[s * 10];
    const float cnt = base[9];
    if (s != 0 && cnt > 0.0f) {
        const float ss = base[8];
        float m2 = 0.0f;
#pragma unroll
        for (int d = 0; d < 8; ++d) {
            const float sd = base[d];
            m2 += sd * sd;
        }
        val = (ss - m2 / cnt) / (cnt * 8.0f);
    }
#pragma unroll
    for (int off = 32; off > 0; off >>= 1) val += __shfl_down(val, off, 64);
    if (s == 0) out[0] = val;
}

extern "C" void kernel_launch(void* const* d_in, const int* in_sizes, int n_in,
                              void* d_out, int out_size, void* d_ws, size_t ws_size,
                              hipStream_t stream) {
    const float* variances = (const float*)d_in[0];  // [N, 8] fp32
    const int* labels = (const int*)d_in[1];         // [N] int32
    const int n = in_sizes[1];                       // N
    float* gacc = (float*)d_ws;                      // 640 floats of scratch

    hipMemsetAsync(d_ws, 0, NUM_INST * 10 * sizeof(float), stream);
    vsl_main<<<GRID, BLOCK, 0, stream>>>(variances, labels, gacc, n);
    vsl_final<<<1, 64, 0, stream>>>(gacc, (float*)d_out);
}